// Round 6
// baseline (50.277 us; speedup 1.0000x reference)
//
#include <hip/hip_runtime.h>

constexpr int RES  = 256;   // image resolution, rays per angle, steps per ray
constexpr int NANG = 180;
constexpr int NB   = 4;

// bf16 quad pack: P[b][ys][xs] = (v00, v10, v01, v11) as 4x bf16 (8 bytes),
// ys,xs in [0,256]; pixel (y,x) = (ys-1, xs-1); out-of-image taps are 0.
constexpr int ROWSQ = RES + 1;   // 257
constexpr int COLSQ = RES + 1;   // 257
constexpr int SXQ   = COLSQ;     // row stride in 8B quads
constexpr size_t PACK_BYTES = (size_t)NB * ROWSQ * SXQ * 8;

typedef float f2_t __attribute__((ext_vector_type(2), aligned(4)));
typedef unsigned int u2_t __attribute__((ext_vector_type(2), aligned(8)));

__device__ inline unsigned bf16_rne(float f)
{
    const unsigned u = __float_as_uint(f);
    return (u + 0x7fffu + ((u >> 16) & 1u)) >> 16;   // RNE; no NaN/Inf inputs
}

// ---------------------------------------------------------------------------
// Pack: one 8B quad per (ys,xs). All cells rewritten every call.
// ---------------------------------------------------------------------------
__global__ __launch_bounds__(256)
void pack_quad(const float* __restrict__ imgs, u2_t* __restrict__ P)
{
    const int ys = blockIdx.x % ROWSQ;
    const int b  = blockIdx.x / ROWSQ;
    const int y  = ys - 1;
    const float* __restrict__ img = imgs + b * (RES * RES);
    u2_t* __restrict__ row = P + ((size_t)b * ROWSQ + ys) * SXQ;

    const bool y0in = (unsigned)y < (unsigned)RES;   // row y   valid
    const bool y1in = ys < RES;                      // row ys  valid (y+1)

    for (int xs = threadIdx.x; xs < COLSQ; xs += 256) {
        const int x = xs - 1;
        const bool x0in = (unsigned)x < (unsigned)RES;
        const bool x1in = xs < RES;
        const float v00 = (y0in && x0in) ? img[y  * RES + x ] : 0.0f;
        const float v10 = (y1in && x0in) ? img[ys * RES + x ] : 0.0f;
        const float v01 = (y0in && x1in) ? img[y  * RES + xs] : 0.0f;
        const float v11 = (y1in && x1in) ? img[ys * RES + xs] : 0.0f;
        u2_t q;
        q.x = bf16_rne(v00) | (bf16_rne(v10) << 16);
        q.y = bf16_rne(v01) | (bf16_rne(v11) << 16);
        row[xs] = q;
    }
}

// ---------------------------------------------------------------------------
// Main: lane = cq*8 + rq (8 rays x 8 consecutive steps -> compact rotated
// ~8x8 px tile per wave-gather). ONE dwordx2 gather per bilinear sample;
// taps pre-zeroed by the guard band -> no boundary logic at all.
// ---------------------------------------------------------------------------
__global__ __launch_bounds__(256)
void radon_fwd_packed(const u2_t* __restrict__ P,
                      const float* __restrict__ angles,
                      const float* __restrict__ rays,
                      float* __restrict__ out)
{
    const int tid  = threadIdx.x;
    const int wave = tid >> 6;
    const int lane = tid & 63;
    const int cq   = lane >> 3;   // step phase 0..7
    const int rq   = lane & 7;    // ray within the wave's 8-ray group

    const int pair = blockIdx.x >> 3;
    const int rblk = blockIdx.x & 7;
    const int a = pair % NANG;
    const int b = pair / NANG;
    const int r = rblk * 32 + wave * 8 + rq;

    const float4 ray = reinterpret_cast<const float4*>(rays)[r];
    float sn, cs;
    sincosf(angles[a], &sn, &cs);

    const float rsx = ray.x * cs - ray.y * sn;
    const float rsy = ray.x * sn + ray.y * cs;
    const float rex = ray.z * cs - ray.w * sn;
    const float rey = ray.z * sn + ray.w * cs;

    const float ddx = rex - rsx;
    const float ddy = rey - rsy;

    // gx = fx + 1 in [0.5, 256.5] -> floor == trunc >= 0; index = x0+1.
    const float tb  = ((float)cq + 0.5f) * (1.0f / 256.0f);
    const float gxb = fmaf(ddx, tb, rsx + 128.5f);
    const float gyb = fmaf(ddy, tb, rsy + 128.5f);

    const u2_t* __restrict__ Pb = P + (size_t)b * ROWSQ * SXQ;

    float acc = 0.0f;
#pragma unroll
    for (int jo = 0; jo < 32; jo += 4) {
        u2_t  q[4];
        float wx[4], wy[4];

        // --- phase 1: addresses, issue 4 independent 8B gathers ---
#pragma unroll
        for (int u = 0; u < 4; ++u) {
            const float jf = (float)(jo + u) * (1.0f / 32.0f);
            const float gx = fmaf(ddx, jf, gxb);
            const float gy = fmaf(ddy, jf, gyb);
            const int   xs = (int)gx;          // trunc == floor (gx > 0)
            const int   ys = (int)gy;
            wx[u] = gx - (float)xs;
            wy[u] = gy - (float)ys;
            q[u] = Pb[ys * SXQ + xs];
        }

        // --- phase 2: unpack bf16 quads + lerp ---
#pragma unroll
        for (int u = 0; u < 4; ++u) {
            const float v00 = __uint_as_float(q[u].x << 16);
            const float v10 = __uint_as_float(q[u].x & 0xffff0000u);
            const float v01 = __uint_as_float(q[u].y << 16);
            const float v11 = __uint_as_float(q[u].y & 0xffff0000u);
            const float top = fmaf(wx[u], v01 - v00, v00);
            const float bot = fmaf(wx[u], v11 - v10, v10);
            acc += fmaf(wy[u], bot - top, top);
        }
    }

    acc *= (ray.w - ray.y) * (1.0f / 256.0f);   // * step

    acc += __shfl_down(acc, 32);
    acc += __shfl_down(acc, 16);
    acc += __shfl_down(acc, 8);

    if (cq == 0)
        out[(b * NANG + a) * RES + r] = acc;
}

// ---------------------------------------------------------------------------
// Fallback (no workspace): reads imgs directly, full f32 path.
// ---------------------------------------------------------------------------
__global__ __launch_bounds__(256)
void radon_fwd_fallback(const float* __restrict__ imgs,
                        const float* __restrict__ angles,
                        const float* __restrict__ rays,
                        float* __restrict__ out)
{
    const int tid  = threadIdx.x;
    const int wave = tid >> 6;
    const int lane = tid & 63;
    const int cq   = lane >> 3;
    const int rq   = lane & 7;

    const int pair = blockIdx.x >> 3;
    const int rblk = blockIdx.x & 7;
    const int a = pair % NANG;
    const int b = pair / NANG;
    const int r = rblk * 32 + wave * 8 + rq;

    const float4 ray = reinterpret_cast<const float4*>(rays)[r];
    float sn, cs;
    sincosf(angles[a], &sn, &cs);

    const float rsx = ray.x * cs - ray.y * sn;
    const float rsy = ray.x * sn + ray.y * cs;
    const float rex = ray.z * cs - ray.w * sn;
    const float rey = ray.z * sn + ray.w * cs;

    const float ddx = rex - rsx;
    const float ddy = rey - rsy;
    const float bx  = rsx + 127.5f;
    const float by  = rsy + 127.5f;

    const float* __restrict__ img = imgs + b * (RES * RES);

    float acc = 0.0f;
#pragma unroll 4
    for (int j = 0; j < 32; ++j) {
        const int   i  = j * 8 + cq;
        const float t  = ((float)i + 0.5f) * (1.0f / 256.0f);
        const float fx = fmaf(ddx, t, bx);
        const float fy = fmaf(ddy, t, by);

        const float x0f = floorf(fx);
        const float y0f = floorf(fy);
        const int   x0  = (int)x0f;
        const int   y0  = (int)y0f;
        const float wxv = fx - x0f;
        const float wyv = fy - y0f;

        const int xs  = min(max(x0, 0), RES - 2);
        const int yc0 = min(max(y0, 0), RES - 1);
        const int yc1 = min(max(y0 + 1, 0), RES - 1);

        const f2_t p0 = *reinterpret_cast<const f2_t*>(img + yc0 * RES + xs);
        const f2_t p1 = *reinterpret_cast<const f2_t*>(img + yc1 * RES + xs);

        const bool straight = (x0 == xs);
        const float v00 = straight ? p0.x : p0.y;
        const float v01 = straight ? p0.y : p0.x;
        const float v10 = straight ? p1.x : p1.y;
        const float v11 = straight ? p1.y : p1.x;

        const bool vx0 = (unsigned)x0       < (unsigned)RES;
        const bool vx1 = (unsigned)(x0 + 1) < (unsigned)RES;
        const bool vy0 = (unsigned)y0       < (unsigned)RES;
        const bool vy1 = (unsigned)(y0 + 1) < (unsigned)RES;
        const float wxa = vx0 ? (1.0f - wxv) : 0.0f;
        const float wxb = vx1 ? wxv          : 0.0f;
        const float wya = vy0 ? (1.0f - wyv) : 0.0f;
        const float wyb = vy1 ? wyv          : 0.0f;

        const float top = wxa * v00 + wxb * v01;
        const float bot = wxa * v10 + wxb * v11;
        acc += wya * top + wyb * bot;
    }

    acc *= (ray.w - ray.y) * (1.0f / 256.0f);

    acc += __shfl_down(acc, 32);
    acc += __shfl_down(acc, 16);
    acc += __shfl_down(acc, 8);

    if (cq == 0)
        out[(b * NANG + a) * RES + r] = acc;
}

extern "C" void kernel_launch(void* const* d_in, const int* in_sizes, int n_in,
                              void* d_out, int out_size, void* d_ws, size_t ws_size,
                              hipStream_t stream)
{
    const float* imgs   = (const float*)d_in[0];
    const float* angles = (const float*)d_in[1];
    const float* rays   = (const float*)d_in[2];
    float* out = (float*)d_out;

    if (ws_size >= PACK_BYTES) {
        u2_t* P = (u2_t*)d_ws;
        pack_quad<<<dim3(NB * ROWSQ), dim3(256), 0, stream>>>(imgs, P);
        radon_fwd_packed<<<dim3(NB * NANG * 8), dim3(256), 0, stream>>>(P, angles, rays, out);
    } else {
        radon_fwd_fallback<<<dim3(NB * NANG * 8), dim3(256), 0, stream>>>(imgs, angles, rays, out);
    }
}

// Round 7
// 37.146 us; speedup vs baseline: 1.3535x; 1.3535x over previous
//
#include <hip/hip_runtime.h>

constexpr int RES  = 256;   // image resolution, rays per angle, steps per ray
constexpr int NANG = 180;
constexpr int NB   = 4;

// Batch-interleaved bf16 quad pack: cell(ys,xs) = 32 B =
//   { b0:(v00|v10<<16, v01|v11<<16), b1:(..), b2:(..), b3:(..) }
// ys,xs in [0,256]; pixel (y,x) = (ys-1, xs-1); out-of-image taps are 0.
constexpr int ROWSQ = RES + 1;   // 257
constexpr int COLSQ = RES + 1;   // 257
constexpr size_t PACK_BYTES = (size_t)ROWSQ * COLSQ * 32;

typedef unsigned int u4_t __attribute__((ext_vector_type(4), aligned(16)));
typedef float f2_t __attribute__((ext_vector_type(2), aligned(4)));

__device__ inline unsigned bf16_rne(float f)
{
    const unsigned u = __float_as_uint(f);
    return (u + 0x7fffu + ((u >> 16) & 1u)) >> 16;   // RNE; no NaN/Inf inputs
}

// ---------------------------------------------------------------------------
// Pack: one 32B cell per (ys,xs) holding all 4 batches' quads.
// All cells rewritten every call (d_ws is poisoned once before timing).
// ---------------------------------------------------------------------------
__global__ __launch_bounds__(256)
void pack_quad4(const float* __restrict__ imgs, u4_t* __restrict__ P)
{
    const int ys = blockIdx.x;       // 0..256
    const int y  = ys - 1;
    const bool y0in = (unsigned)y < (unsigned)RES;
    const bool y1in = ys < RES;

    for (int xs = threadIdx.x; xs < COLSQ; xs += 256) {
        const int x = xs - 1;
        const bool x0in = (unsigned)x < (unsigned)RES;
        const bool x1in = xs < RES;

        unsigned lo[NB], hi[NB];
#pragma unroll
        for (int b = 0; b < NB; ++b) {
            const float* __restrict__ img = imgs + b * (RES * RES);
            const float v00 = (y0in && x0in) ? img[y  * RES + x ] : 0.0f;
            const float v10 = (y1in && x0in) ? img[ys * RES + x ] : 0.0f;
            const float v01 = (y0in && x1in) ? img[y  * RES + xs] : 0.0f;
            const float v11 = (y1in && x1in) ? img[ys * RES + xs] : 0.0f;
            lo[b] = bf16_rne(v00) | (bf16_rne(v10) << 16);
            hi[b] = bf16_rne(v01) | (bf16_rne(v11) << 16);
        }
        u4_t qa, qb;
        qa.x = lo[0]; qa.y = hi[0]; qa.z = lo[1]; qa.w = hi[1];
        qb.x = lo[2]; qb.y = hi[2]; qb.z = lo[3]; qb.w = hi[3];
        u4_t* cell = P + (size_t)(ys * COLSQ + xs) * 2;
        cell[0] = qa;
        cell[1] = qb;
    }
}

__device__ inline float lerpq(unsigned lo, unsigned hi, float wx, float wy,
                              float acc)
{
    const float v00 = __uint_as_float(lo << 16);
    const float v10 = __uint_as_float(lo & 0xffff0000u);
    const float v01 = __uint_as_float(hi << 16);
    const float v11 = __uint_as_float(hi & 0xffff0000u);
    const float top = fmaf(wx, v01 - v00, v00);
    const float bot = fmaf(wx, v11 - v10, v10);
    return acc + fmaf(wy, bot - top, top);
}

// ---------------------------------------------------------------------------
// Main: 128 threads = 2 waves; lane = cq*8 + rq (8 rays x 8 step-phases ->
// compact rotated ~8x8 px tile per wave-gather). ONE address per 4 batch-
// samples: two dwordx4 loads from the same 32B cell. Guard band -> no
// boundary logic.
// ---------------------------------------------------------------------------
__global__ __launch_bounds__(128)
void radon_fwd_b4(const u4_t* __restrict__ P,
                  const float* __restrict__ angles,
                  const float* __restrict__ rays,
                  float* __restrict__ out)
{
    const int tid  = threadIdx.x;
    const int wave = tid >> 6;
    const int lane = tid & 63;
    const int cq   = lane >> 3;   // step phase 0..7
    const int rq   = lane & 7;    // ray within the wave's 8-ray group

    const int a    = blockIdx.x >> 4;     // angle
    const int rblk = blockIdx.x & 15;     // 16-ray block
    const int r    = rblk * 16 + wave * 8 + rq;

    const float4 ray = reinterpret_cast<const float4*>(rays)[r];
    float sn, cs;
    sincosf(angles[a], &sn, &cs);

    const float rsx = ray.x * cs - ray.y * sn;
    const float rsy = ray.x * sn + ray.y * cs;
    const float rex = ray.z * cs - ray.w * sn;
    const float rey = ray.z * sn + ray.w * cs;

    const float ddx = rex - rsx;
    const float ddy = rey - rsy;

    // gx = fx + 1 in [0.5, 256.5] -> floor == trunc >= 0; index = x0+1.
    const float tb  = ((float)cq + 0.5f) * (1.0f / 256.0f);
    const float gxb = fmaf(ddx, tb, rsx + 128.5f);
    const float gyb = fmaf(ddy, tb, rsy + 128.5f);

    float acc0 = 0.0f, acc1 = 0.0f, acc2 = 0.0f, acc3 = 0.0f;

#pragma unroll
    for (int jo = 0; jo < 32; jo += 4) {
        u4_t  qa[4], qb[4];
        float wx[4], wy[4];

        // --- phase 1: addresses, issue 8 independent 16B gathers ---
#pragma unroll
        for (int u = 0; u < 4; ++u) {
            const float jf = (float)(jo + u) * (1.0f / 32.0f);
            const float gx = fmaf(ddx, jf, gxb);
            const float gy = fmaf(ddy, jf, gyb);
            const int   xs = (int)gx;          // trunc == floor (gx > 0)
            const int   ys = (int)gy;
            wx[u] = gx - (float)xs;
            wy[u] = gy - (float)ys;
            const u4_t* cell = P + (size_t)(ys * COLSQ + xs) * 2;
            qa[u] = cell[0];
            qb[u] = cell[1];
        }

        // --- phase 2: unpack + lerp, 4 batches per position ---
#pragma unroll
        for (int u = 0; u < 4; ++u) {
            acc0 = lerpq(qa[u].x, qa[u].y, wx[u], wy[u], acc0);
            acc1 = lerpq(qa[u].z, qa[u].w, wx[u], wy[u], acc1);
            acc2 = lerpq(qb[u].x, qb[u].y, wx[u], wy[u], acc2);
            acc3 = lerpq(qb[u].z, qb[u].w, wx[u], wy[u], acc3);
        }
    }

    const float scale = (ray.w - ray.y) * (1.0f / 256.0f);   // step
    acc0 *= scale; acc1 *= scale; acc2 *= scale; acc3 *= scale;

    // reduce over the 8 step-phases (cq axis, stride 8 in lane space)
    acc0 += __shfl_down(acc0, 32); acc1 += __shfl_down(acc1, 32);
    acc2 += __shfl_down(acc2, 32); acc3 += __shfl_down(acc3, 32);
    acc0 += __shfl_down(acc0, 16); acc1 += __shfl_down(acc1, 16);
    acc2 += __shfl_down(acc2, 16); acc3 += __shfl_down(acc3, 16);
    acc0 += __shfl_down(acc0, 8);  acc1 += __shfl_down(acc1, 8);
    acc2 += __shfl_down(acc2, 8);  acc3 += __shfl_down(acc3, 8);

    if (cq == 0) {
        const int o = a * RES + r;
        out[0 * NANG * RES + o] = acc0;
        out[1 * NANG * RES + o] = acc1;
        out[2 * NANG * RES + o] = acc2;
        out[3 * NANG * RES + o] = acc3;
    }
}

// ---------------------------------------------------------------------------
// Fallback (no workspace): reads imgs directly, full f32 path.
// ---------------------------------------------------------------------------
__global__ __launch_bounds__(256)
void radon_fwd_fallback(const float* __restrict__ imgs,
                        const float* __restrict__ angles,
                        const float* __restrict__ rays,
                        float* __restrict__ out)
{
    const int tid  = threadIdx.x;
    const int wave = tid >> 6;
    const int lane = tid & 63;
    const int cq   = lane >> 3;
    const int rq   = lane & 7;

    const int pair = blockIdx.x >> 3;
    const int rblk = blockIdx.x & 7;
    const int a = pair % NANG;
    const int b = pair / NANG;
    const int r = rblk * 32 + wave * 8 + rq;

    const float4 ray = reinterpret_cast<const float4*>(rays)[r];
    float sn, cs;
    sincosf(angles[a], &sn, &cs);

    const float rsx = ray.x * cs - ray.y * sn;
    const float rsy = ray.x * sn + ray.y * cs;
    const float rex = ray.z * cs - ray.w * sn;
    const float rey = ray.z * sn + ray.w * cs;

    const float ddx = rex - rsx;
    const float ddy = rey - rsy;
    const float bx  = rsx + 127.5f;
    const float by  = rsy + 127.5f;

    const float* __restrict__ img = imgs + b * (RES * RES);

    float acc = 0.0f;
#pragma unroll 4
    for (int j = 0; j < 32; ++j) {
        const int   i  = j * 8 + cq;
        const float t  = ((float)i + 0.5f) * (1.0f / 256.0f);
        const float fx = fmaf(ddx, t, bx);
        const float fy = fmaf(ddy, t, by);

        const float x0f = floorf(fx);
        const float y0f = floorf(fy);
        const int   x0  = (int)x0f;
        const int   y0  = (int)y0f;
        const float wxv = fx - x0f;
        const float wyv = fy - y0f;

        const int xs  = min(max(x0, 0), RES - 2);
        const int yc0 = min(max(y0, 0), RES - 1);
        const int yc1 = min(max(y0 + 1, 0), RES - 1);

        const f2_t p0 = *reinterpret_cast<const f2_t*>(img + yc0 * RES + xs);
        const f2_t p1 = *reinterpret_cast<const f2_t*>(img + yc1 * RES + xs);

        const bool straight = (x0 == xs);
        const float v00 = straight ? p0.x : p0.y;
        const float v01 = straight ? p0.y : p0.x;
        const float v10 = straight ? p1.x : p1.y;
        const float v11 = straight ? p1.y : p1.x;

        const bool vx0 = (unsigned)x0       < (unsigned)RES;
        const bool vx1 = (unsigned)(x0 + 1) < (unsigned)RES;
        const bool vy0 = (unsigned)y0       < (unsigned)RES;
        const bool vy1 = (unsigned)(y0 + 1) < (unsigned)RES;
        const float wxa = vx0 ? (1.0f - wxv) : 0.0f;
        const float wxb = vx1 ? wxv          : 0.0f;
        const float wya = vy0 ? (1.0f - wyv) : 0.0f;
        const float wyb = vy1 ? wyv          : 0.0f;

        const float top = wxa * v00 + wxb * v01;
        const float bot = wxa * v10 + wxb * v11;
        acc += wya * top + wyb * bot;
    }

    acc *= (ray.w - ray.y) * (1.0f / 256.0f);

    acc += __shfl_down(acc, 32);
    acc += __shfl_down(acc, 16);
    acc += __shfl_down(acc, 8);

    if (cq == 0)
        out[(b * NANG + a) * RES + r] = acc;
}

extern "C" void kernel_launch(void* const* d_in, const int* in_sizes, int n_in,
                              void* d_out, int out_size, void* d_ws, size_t ws_size,
                              hipStream_t stream)
{
    const float* imgs   = (const float*)d_in[0];
    const float* angles = (const float*)d_in[1];
    const float* rays   = (const float*)d_in[2];
    float* out = (float*)d_out;

    if (ws_size >= PACK_BYTES) {
        u4_t* P = (u4_t*)d_ws;
        pack_quad4<<<dim3(ROWSQ), dim3(256), 0, stream>>>(imgs, P);
        radon_fwd_b4<<<dim3(NANG * 16), dim3(128), 0, stream>>>(P, angles, rays, out);
    } else {
        radon_fwd_fallback<<<dim3(NB * NANG * 8), dim3(256), 0, stream>>>(imgs, angles, rays, out);
    }
}

// Round 8
// 36.637 us; speedup vs baseline: 1.3723x; 1.0139x over previous
//
#include <hip/hip_runtime.h>

constexpr int RES  = 256;   // image resolution, rays per angle, steps per ray
constexpr int NANG = 180;
constexpr int NB   = 4;

// Split batch-pair bf16 quad pack:
//   P01[idx] = { b0:(v00|v10, v01|v11), b1:(...) }   16 B cells
//   P23[idx] = { b2:(...),              b3:(...) }   16 B cells
// idx = ys*COLSQ+xs, ys,xs in [0,256]; pixel (y,x) = (ys-1,xs-1);
// out-of-image taps are exactly 0 (guard band) -> no boundary logic.
constexpr int ROWSQ = RES + 1;   // 257
constexpr int COLSQ = RES + 1;   // 257
constexpr size_t NCELLS = (size_t)ROWSQ * COLSQ;
constexpr size_t PACK_BYTES = NCELLS * 32;   // two 16B arrays

typedef unsigned int u4_t __attribute__((ext_vector_type(4), aligned(16)));
typedef float f2_t __attribute__((ext_vector_type(2), aligned(4)));

__device__ inline unsigned bf16_rne(float f)
{
    const unsigned u = __float_as_uint(f);
    return (u + 0x7fffu + ((u >> 16) & 1u)) >> 16;   // RNE; no NaN/Inf inputs
}

// ---------------------------------------------------------------------------
// Pack: one 16B cell per (ys,xs) in each of P01/P23. All cells rewritten
// every call (d_ws is poisoned once before timing).
// ---------------------------------------------------------------------------
__global__ __launch_bounds__(256)
void pack_split(const float* __restrict__ imgs,
                u4_t* __restrict__ P01, u4_t* __restrict__ P23)
{
    const int ys = blockIdx.x;       // 0..256
    const int y  = ys - 1;
    const bool y0in = (unsigned)y < (unsigned)RES;
    const bool y1in = ys < RES;

    for (int xs = threadIdx.x; xs < COLSQ; xs += 256) {
        const int x = xs - 1;
        const bool x0in = (unsigned)x < (unsigned)RES;
        const bool x1in = xs < RES;

        unsigned lo[NB], hi[NB];
#pragma unroll
        for (int b = 0; b < NB; ++b) {
            const float* __restrict__ img = imgs + b * (RES * RES);
            const float v00 = (y0in && x0in) ? img[y  * RES + x ] : 0.0f;
            const float v10 = (y1in && x0in) ? img[ys * RES + x ] : 0.0f;
            const float v01 = (y0in && x1in) ? img[y  * RES + xs] : 0.0f;
            const float v11 = (y1in && x1in) ? img[ys * RES + xs] : 0.0f;
            lo[b] = bf16_rne(v00) | (bf16_rne(v10) << 16);
            hi[b] = bf16_rne(v01) | (bf16_rne(v11) << 16);
        }
        const int idx = ys * COLSQ + xs;
        u4_t qa, qb;
        qa.x = lo[0]; qa.y = hi[0]; qa.z = lo[1]; qa.w = hi[1];
        qb.x = lo[2]; qb.y = hi[2]; qb.z = lo[3]; qb.w = hi[3];
        P01[idx] = qa;
        P23[idx] = qb;
    }
}

__device__ inline float lerpq(unsigned lo, unsigned hi, float wx, float wy,
                              float acc)
{
    const float v00 = __uint_as_float(lo << 16);
    const float v10 = __uint_as_float(lo & 0xffff0000u);
    const float v01 = __uint_as_float(hi << 16);
    const float v11 = __uint_as_float(hi & 0xffff0000u);
    const float top = fmaf(wx, v01 - v00, v00);
    const float bot = fmaf(wx, v11 - v10, v10);
    return acc + fmaf(wy, bot - top, top);
}

// ---------------------------------------------------------------------------
// Main: 128 threads = 2 waves; lane = cq*8 + rq (8 rays x 8 step-phases ->
// compact rotated ~8x8 px tile per wave-gather). One address per 4 batch-
// samples; two dwordx4 loads from the two SPLIT arrays (dense 1KB footprint
// per instruction -> ~18 lines, under the ~39-cyc TA address floor).
// ---------------------------------------------------------------------------
__global__ __launch_bounds__(128)
void radon_fwd_b4(const u4_t* __restrict__ P01,
                  const u4_t* __restrict__ P23,
                  const float* __restrict__ angles,
                  const float* __restrict__ rays,
                  float* __restrict__ out)
{
    const int tid  = threadIdx.x;
    const int wave = tid >> 6;
    const int lane = tid & 63;
    const int cq   = lane >> 3;   // step phase 0..7
    const int rq   = lane & 7;    // ray within the wave's 8-ray group

    const int a    = blockIdx.x >> 4;     // angle
    const int rblk = blockIdx.x & 15;     // 16-ray block
    const int r    = rblk * 16 + wave * 8 + rq;

    const float4 ray = reinterpret_cast<const float4*>(rays)[r];
    float sn, cs;
    sincosf(angles[a], &sn, &cs);

    const float rsx = ray.x * cs - ray.y * sn;
    const float rsy = ray.x * sn + ray.y * cs;
    const float rex = ray.z * cs - ray.w * sn;
    const float rey = ray.z * sn + ray.w * cs;

    const float ddx = rex - rsx;
    const float ddy = rey - rsy;

    // gx = fx + 1 in [0.5, 256.5] -> floor == trunc >= 0; index = x0+1.
    const float tb  = ((float)cq + 0.5f) * (1.0f / 256.0f);
    const float gxb = fmaf(ddx, tb, rsx + 128.5f);
    const float gyb = fmaf(ddy, tb, rsy + 128.5f);

    float acc0 = 0.0f, acc1 = 0.0f, acc2 = 0.0f, acc3 = 0.0f;

#pragma unroll
    for (int jo = 0; jo < 32; jo += 4) {
        u4_t  qa[4], qb[4];
        float wx[4], wy[4];

        // --- phase 1: addresses, issue 8 independent 16B gathers ---
#pragma unroll
        for (int u = 0; u < 4; ++u) {
            const float jf = (float)(jo + u) * (1.0f / 32.0f);
            const float gx = fmaf(ddx, jf, gxb);
            const float gy = fmaf(ddy, jf, gyb);
            const int   xs = (int)gx;          // trunc == floor (gx > 0)
            const int   ys = (int)gy;
            wx[u] = gx - (float)xs;
            wy[u] = gy - (float)ys;
            const int idx = ys * COLSQ + xs;   // shared voffset for both arrays
            qa[u] = P01[idx];
            qb[u] = P23[idx];
        }

        // --- phase 2: unpack + lerp, 4 batches per position ---
#pragma unroll
        for (int u = 0; u < 4; ++u) {
            acc0 = lerpq(qa[u].x, qa[u].y, wx[u], wy[u], acc0);
            acc1 = lerpq(qa[u].z, qa[u].w, wx[u], wy[u], acc1);
            acc2 = lerpq(qb[u].x, qb[u].y, wx[u], wy[u], acc2);
            acc3 = lerpq(qb[u].z, qb[u].w, wx[u], wy[u], acc3);
        }
    }

    const float scale = (ray.w - ray.y) * (1.0f / 256.0f);   // step
    acc0 *= scale; acc1 *= scale; acc2 *= scale; acc3 *= scale;

    // reduce over the 8 step-phases (cq axis, stride 8 in lane space)
    acc0 += __shfl_down(acc0, 32); acc1 += __shfl_down(acc1, 32);
    acc2 += __shfl_down(acc2, 32); acc3 += __shfl_down(acc3, 32);
    acc0 += __shfl_down(acc0, 16); acc1 += __shfl_down(acc1, 16);
    acc2 += __shfl_down(acc2, 16); acc3 += __shfl_down(acc3, 16);
    acc0 += __shfl_down(acc0, 8);  acc1 += __shfl_down(acc1, 8);
    acc2 += __shfl_down(acc2, 8);  acc3 += __shfl_down(acc3, 8);

    if (cq == 0) {
        const int o = a * RES + r;
        out[0 * NANG * RES + o] = acc0;
        out[1 * NANG * RES + o] = acc1;
        out[2 * NANG * RES + o] = acc2;
        out[3 * NANG * RES + o] = acc3;
    }
}

// ---------------------------------------------------------------------------
// Fallback (no workspace): reads imgs directly, full f32 path.
// ---------------------------------------------------------------------------
__global__ __launch_bounds__(256)
void radon_fwd_fallback(const float* __restrict__ imgs,
                        const float* __restrict__ angles,
                        const float* __restrict__ rays,
                        float* __restrict__ out)
{
    const int tid  = threadIdx.x;
    const int wave = tid >> 6;
    const int lane = tid & 63;
    const int cq   = lane >> 3;
    const int rq   = lane & 7;

    const int pair = blockIdx.x >> 3;
    const int rblk = blockIdx.x & 7;
    const int a = pair % NANG;
    const int b = pair / NANG;
    const int r = rblk * 32 + wave * 8 + rq;

    const float4 ray = reinterpret_cast<const float4*>(rays)[r];
    float sn, cs;
    sincosf(angles[a], &sn, &cs);

    const float rsx = ray.x * cs - ray.y * sn;
    const float rsy = ray.x * sn + ray.y * cs;
    const float rex = ray.z * cs - ray.w * sn;
    const float rey = ray.z * sn + ray.w * cs;

    const float ddx = rex - rsx;
    const float ddy = rey - rsy;
    const float bx  = rsx + 127.5f;
    const float by  = rsy + 127.5f;

    const float* __restrict__ img = imgs + b * (RES * RES);

    float acc = 0.0f;
#pragma unroll 4
    for (int j = 0; j < 32; ++j) {
        const int   i  = j * 8 + cq;
        const float t  = ((float)i + 0.5f) * (1.0f / 256.0f);
        const float fx = fmaf(ddx, t, bx);
        const float fy = fmaf(ddy, t, by);

        const float x0f = floorf(fx);
        const float y0f = floorf(fy);
        const int   x0  = (int)x0f;
        const int   y0  = (int)y0f;
        const float wxv = fx - x0f;
        const float wyv = fy - y0f;

        const int xs  = min(max(x0, 0), RES - 2);
        const int yc0 = min(max(y0, 0), RES - 1);
        const int yc1 = min(max(y0 + 1, 0), RES - 1);

        const f2_t p0 = *reinterpret_cast<const f2_t*>(img + yc0 * RES + xs);
        const f2_t p1 = *reinterpret_cast<const f2_t*>(img + yc1 * RES + xs);

        const bool straight = (x0 == xs);
        const float v00 = straight ? p0.x : p0.y;
        const float v01 = straight ? p0.y : p0.x;
        const float v10 = straight ? p1.x : p1.y;
        const float v11 = straight ? p1.y : p1.x;

        const bool vx0 = (unsigned)x0       < (unsigned)RES;
        const bool vx1 = (unsigned)(x0 + 1) < (unsigned)RES;
        const bool vy0 = (unsigned)y0       < (unsigned)RES;
        const bool vy1 = (unsigned)(y0 + 1) < (unsigned)RES;
        const float wxa = vx0 ? (1.0f - wxv) : 0.0f;
        const float wxb = vx1 ? wxv          : 0.0f;
        const float wya = vy0 ? (1.0f - wyv) : 0.0f;
        const float wyb = vy1 ? wyv          : 0.0f;

        const float top = wxa * v00 + wxb * v01;
        const float bot = wxa * v10 + wxb * v11;
        acc += wya * top + wyb * bot;
    }

    acc *= (ray.w - ray.y) * (1.0f / 256.0f);

    acc += __shfl_down(acc, 32);
    acc += __shfl_down(acc, 16);
    acc += __shfl_down(acc, 8);

    if (cq == 0)
        out[(b * NANG + a) * RES + r] = acc;
}

extern "C" void kernel_launch(void* const* d_in, const int* in_sizes, int n_in,
                              void* d_out, int out_size, void* d_ws, size_t ws_size,
                              hipStream_t stream)
{
    const float* imgs   = (const float*)d_in[0];
    const float* angles = (const float*)d_in[1];
    const float* rays   = (const float*)d_in[2];
    float* out = (float*)d_out;

    if (ws_size >= PACK_BYTES) {
        u4_t* P01 = (u4_t*)d_ws;
        u4_t* P23 = P01 + NCELLS;
        pack_split<<<dim3(ROWSQ), dim3(256), 0, stream>>>(imgs, P01, P23);
        radon_fwd_b4<<<dim3(NANG * 16), dim3(128), 0, stream>>>(P01, P23, angles, rays, out);
    } else {
        radon_fwd_fallback<<<dim3(NB * NANG * 8), dim3(256), 0, stream>>>(imgs, angles, rays, out);
    }
}